// Round 4
// baseline (730.529 us; speedup 1.0000x reference)
//
#include <hip/hip_runtime.h>
#include <stdint.h>

#define B_ 8
#define C_ 256
#define D_ 128
#define N_ 4096

typedef __bf16 bf16x8 __attribute__((ext_vector_type(8)));
typedef uint16_t u16x8 __attribute__((ext_vector_type(8)));
typedef uint16_t u16x4 __attribute__((ext_vector_type(4)));
typedef float f32x4 __attribute__((ext_vector_type(4)));

__device__ inline uint16_t f2bf(float x) {
    union { float f; uint32_t u; } v; v.f = x;
    uint32_t u = v.u;
    return (uint16_t)((u + 0x7FFFu + ((u >> 16) & 1u)) >> 16);
}

// ---------------- prep: fp32 weights -> bf16 (scale 1/sqrt(D) folded into W_theta)
__global__ __launch_bounds__(256) void prep_weights(
    const float* __restrict__ wt, const float* __restrict__ wp,
    const float* __restrict__ wg, const float* __restrict__ wo,
    uint16_t* __restrict__ bwt, uint16_t* __restrict__ bwp,
    uint16_t* __restrict__ bwg, uint16_t* __restrict__ bwo)
{
    int i = blockIdx.x * 256 + threadIdx.x;   // 0..32767
    const float scale = 0.08838834764831845f; // 1/sqrt(128)
    bwt[i] = f2bf(wt[i] * scale);
    bwp[i] = f2bf(wp[i]);
    bwg[i] = f2bf(wg[i]);
    bwo[i] = f2bf(wo[i]);
}

// ---------------- projections: z=0 qp[B][N][D], z=1 kp[B][N][D], z=2 vpT[B][D][N]
__global__ __launch_bounds__(256) void proj_kernel(
    const float* __restrict__ q, const float* __restrict__ k, const float* __restrict__ v,
    const uint16_t* __restrict__ bwt, const uint16_t* __restrict__ bwp, const uint16_t* __restrict__ bwg,
    uint16_t* __restrict__ qp, uint16_t* __restrict__ kp, uint16_t* __restrict__ vpT)
{
    const int which = blockIdx.z;
    const float* src = (which == 0) ? q : ((which == 1) ? k : v);
    const uint16_t* w = (which == 0) ? bwt : ((which == 1) ? bwp : bwg);
    const int b   = blockIdx.y;
    const int n0  = blockIdx.x * 64;
    const int wav = threadIdx.x >> 6;
    const int lane = threadIdx.x & 63;
    const int col = lane & 15;
    const int quad = lane >> 4;
    const int n = n0 + wav * 16 + col;

    const float* srcb = src + (size_t)b * C_ * N_;

    f32x4 acc[8];
#pragma unroll
    for (int mf = 0; mf < 8; ++mf) acc[mf] = (f32x4){0.f, 0.f, 0.f, 0.f};

    for (int kc = 0; kc < 8; ++kc) {
        const int cbase = kc * 32 + quad * 8;
        u16x8 bb;
#pragma unroll
        for (int j = 0; j < 8; ++j)
            bb[j] = f2bf(srcb[(size_t)(cbase + j) * N_ + n]);
        bf16x8 bfrag = __builtin_bit_cast(bf16x8, bb);
#pragma unroll
        for (int mf = 0; mf < 8; ++mf) {
            bf16x8 afrag = *(const bf16x8*)(w + (size_t)(mf * 16 + col) * C_ + cbase);
            acc[mf] = __builtin_amdgcn_mfma_f32_16x16x32_bf16(afrag, bfrag, acc[mf], 0, 0, 0);
        }
    }

    if (which < 2) {
        uint16_t* dst = (which == 0) ? qp : kp;          // [B][N][D], d contiguous
        uint16_t* base = dst + ((size_t)b * N_ + n) * D_;
#pragma unroll
        for (int mf = 0; mf < 8; ++mf) {
            u16x4 pk;
#pragma unroll
            for (int r = 0; r < 4; ++r) pk[r] = f2bf(acc[mf][r]);
            *(u16x4*)(base + mf * 16 + quad * 4) = pk;
        }
    } else {
        uint16_t* base = vpT + (size_t)b * D_ * N_;       // [B][D][N], n contiguous
#pragma unroll
        for (int mf = 0; mf < 8; ++mf)
#pragma unroll
            for (int r = 0; r < 4; ++r) {
                int d = mf * 16 + quad * 4 + r;
                base[(size_t)d * N_ + n] = f2bf(acc[mf][r]);
            }
    }
}

// ---------------- pass 1: inv_denom[b][m] = 1 / sum_n exp(S[n][m])
__global__ __launch_bounds__(256) void pass1_denom(
    const uint16_t* __restrict__ qp, const uint16_t* __restrict__ kp,
    float* __restrict__ inv_denom)
{
    const int b  = blockIdx.y;
    const int m0 = blockIdx.x * 64;
    const int wav = threadIdx.x >> 6;
    const int lane = threadIdx.x & 63;
    const int col = lane & 15;
    const int quad = lane >> 4;

    const uint16_t* qpb = qp + (size_t)b * N_ * D_;
    const uint16_t* kpb = kp + (size_t)b * N_ * D_;

    bf16x8 bfr[4][4];
#pragma unroll
    for (int mf = 0; mf < 4; ++mf)
#pragma unroll
        for (int kc = 0; kc < 4; ++kc)
            bfr[mf][kc] = *(const bf16x8*)(kpb + (size_t)(m0 + mf * 16 + col) * D_ + kc * 32 + quad * 8);

    float colsum[4] = {0.f, 0.f, 0.f, 0.f};

    for (int it = 0; it < 64; ++it) {
        const int nbase = it * 64 + wav * 16;
        bf16x8 afr[4];
#pragma unroll
        for (int kc = 0; kc < 4; ++kc)
            afr[kc] = *(const bf16x8*)(qpb + (size_t)(nbase + col) * D_ + kc * 32 + quad * 8);
#pragma unroll
        for (int mf = 0; mf < 4; ++mf) {
            f32x4 acc = (f32x4){0.f, 0.f, 0.f, 0.f};
#pragma unroll
            for (int kc = 0; kc < 4; ++kc)
                acc = __builtin_amdgcn_mfma_f32_16x16x32_bf16(afr[kc], bfr[mf][kc], acc, 0, 0, 0);
#pragma unroll
            for (int r = 0; r < 4; ++r)
                colsum[mf] += __expf(acc[r]);
        }
    }

    __shared__ float cs[4][64];
#pragma unroll
    for (int mf = 0; mf < 4; ++mf) {
        float s = colsum[mf];
        s += __shfl_down(s, 16, 64);
        s += __shfl_down(s, 32, 64);
        if (quad == 0) cs[wav][mf * 16 + col] = s;
    }
    __syncthreads();
    if (threadIdx.x < 64) {
        float s = cs[0][threadIdx.x] + cs[1][threadIdx.x] + cs[2][threadIdx.x] + cs[3][threadIdx.x];
        inv_denom[(size_t)b * N_ + m0 + threadIdx.x] = 1.0f / s;
    }
}

// ---------------- pass 2: O[n][d] = sum_m exp(S[n][m]) * inv_denom[m] * vp[m][d]
// Round-4: loop-carried register double-buffer. Frags for chunk i+1 are loaded
// while chunk i computes; values cross the loop back-edge so the scheduler CANNOT
// sink them to their uses (round-3 failure mode: VGPR=52, loads re-serialized).
// sched_barrier(0) pins load-batch / compute-half ordering. Unrolled x2, no copies.
__global__ __launch_bounds__(256, 2) void pass2_attn(
    const uint16_t* __restrict__ qp, const uint16_t* __restrict__ kp,
    const uint16_t* __restrict__ vpT, const float* __restrict__ inv_denom,
    uint16_t* __restrict__ obuf)
{
    const int b  = blockIdx.y;
    const int n0 = blockIdx.x * 64;
    const int wav = threadIdx.x >> 6;
    const int lane = threadIdx.x & 63;
    const int col = lane & 15;
    const int quad = lane >> 4;

    const uint16_t* qpb = qp + (size_t)b * N_ * D_;
    const uint16_t* kpb = kp + (size_t)b * N_ * D_;
    const uint16_t* vtb = vpT + (size_t)b * D_ * N_;
    const float* invd = inv_denom + (size_t)b * N_;

    __shared__ __align__(16) uint16_t plds_all[4][16][40];  // +8 pad breaks b128 read conflicts
    uint16_t (*plds)[40] = plds_all[wav];

    const int nrow = n0 + wav * 16 + col;
    bf16x8 qfr[4];
#pragma unroll
    for (int kc = 0; kc < 4; ++kc)
        qfr[kc] = *(const bf16x8*)(qpb + (size_t)nrow * D_ + kc * 32 + quad * 8);

    f32x4 oacc[8];
#pragma unroll
    for (int df = 0; df < 8; ++df) oacc[df] = (f32x4){0.f, 0.f, 0.f, 0.f};

    // lane-local base pointers
    const uint16_t* kp_l = kpb + (size_t)col * D_ + quad * 8;   // + m*D_ + kc*32
    const uint16_t* vt_l = vtb + (size_t)col * N_ + quad * 8;   // + (df*16)*N_ + m0

    bf16x8 ka[8], va[8], kb[8], vb[8];
    float ia[2], ib[2];

#define LOADSET(mbase, K, V, I)                                                     \
    {                                                                               \
        const int _m = (mbase);                                                     \
        _Pragma("unroll")                                                           \
        for (int f = 0; f < 2; ++f)                                                 \
            _Pragma("unroll")                                                       \
            for (int kc = 0; kc < 4; ++kc)                                          \
                K[f * 4 + kc] = *(const bf16x8*)(kp_l + (size_t)(_m + f * 16) * D_ + kc * 32); \
        _Pragma("unroll")                                                           \
        for (int df = 0; df < 8; ++df)                                              \
            V[df] = *(const bf16x8*)(vt_l + (size_t)(df * 16) * N_ + _m);           \
        I[0] = invd[_m + col];                                                      \
        I[1] = invd[_m + 16 + col];                                                 \
    }

#define COMPUTE(mbase, K, V, I)                                                     \
    {                                                                               \
        _Pragma("unroll")                                                           \
        for (int f = 0; f < 2; ++f) {                                               \
            f32x4 sacc = (f32x4){0.f, 0.f, 0.f, 0.f};                               \
            _Pragma("unroll")                                                       \
            for (int kc = 0; kc < 4; ++kc)                                          \
                sacc = __builtin_amdgcn_mfma_f32_16x16x32_bf16(qfr[kc], K[f * 4 + kc], sacc, 0, 0, 0); \
            const float inv = I[f];                                                 \
            _Pragma("unroll")                                                       \
            for (int r = 0; r < 4; ++r)                                             \
                plds[quad * 4 + r][f * 16 + col] = f2bf(__expf(sacc[r]) * inv);     \
        }                                                                           \
        bf16x8 pfrag = *(const bf16x8*)&plds[col][quad * 8];                        \
        _Pragma("unroll")                                                           \
        for (int df = 0; df < 8; ++df)                                              \
            oacc[df] = __builtin_amdgcn_mfma_f32_16x16x32_bf16(pfrag, V[df], oacc[df], 0, 0, 0); \
    }

    LOADSET(0, ka, va, ia);                       // prologue

    for (int m0 = 0; m0 < N_; m0 += 64) {
        LOADSET(m0 + 32, kb, vb, ib);             // prefetch half B
        __builtin_amdgcn_sched_barrier(0);
        COMPUTE(m0, ka, va, ia);                  // compute half A (covers B's latency)
        __builtin_amdgcn_sched_barrier(0);
        LOADSET((m0 + 64) & (N_ - 1), ka, va, ia);// prefetch next half A (wraps harmlessly)
        __builtin_amdgcn_sched_barrier(0);
        COMPUTE(m0 + 32, kb, vb, ib);             // compute half B (covers A's latency)
        __builtin_amdgcn_sched_barrier(0);
    }
#undef LOADSET
#undef COMPUTE

    uint16_t* ob = obuf + ((size_t)b * N_ + n0 + wav * 16) * D_;   // [B][N][D]
#pragma unroll
    for (int df = 0; df < 8; ++df)
#pragma unroll
        for (int r = 0; r < 4; ++r)
            ob[(size_t)(quad * 4 + r) * D_ + df * 16 + col] = f2bf(oacc[df][r]);
}

// ---------------- pass 3: out[b][c][n] = v[b][c][n] + sum_d W_out[c][d] * O[n][d]
__global__ __launch_bounds__(256) void pass3_out(
    const uint16_t* __restrict__ obuf, const uint16_t* __restrict__ bwo,
    const float* __restrict__ v, float* __restrict__ out)
{
    const int b  = blockIdx.y;
    const int n0 = blockIdx.x * 64;
    const int wav = threadIdx.x >> 6;
    const int lane = threadIdx.x & 63;
    const int col = lane & 15;
    const int quad = lane >> 4;
    const int n = n0 + wav * 16 + col;

    const uint16_t* ob = obuf + (size_t)b * N_ * D_;
    const float* vb = v + (size_t)b * C_ * N_;
    float* outb = out + (size_t)b * C_ * N_;

    bf16x8 bfr[4];
#pragma unroll
    for (int kc = 0; kc < 4; ++kc)
        bfr[kc] = *(const bf16x8*)(ob + (size_t)n * D_ + kc * 32 + quad * 8);

#pragma unroll
    for (int cf = 0; cf < 16; ++cf) {
        f32x4 acc = (f32x4){0.f, 0.f, 0.f, 0.f};
#pragma unroll
        for (int kc = 0; kc < 4; ++kc) {
            bf16x8 afr = *(const bf16x8*)(bwo + (size_t)(cf * 16 + col) * D_ + kc * 32 + quad * 8);
            acc = __builtin_amdgcn_mfma_f32_16x16x32_bf16(afr, bfr[kc], acc, 0, 0, 0);
        }
#pragma unroll
        for (int r = 0; r < 4; ++r) {
            const int c = cf * 16 + quad * 4 + r;
            const size_t idx = (size_t)c * N_ + n;
            outb[idx] = vb[idx] + acc[r];
        }
    }
}

extern "C" void kernel_launch(void* const* d_in, const int* in_sizes, int n_in,
                              void* d_out, int out_size, void* d_ws, size_t ws_size,
                              hipStream_t stream) {
    const float* q  = (const float*)d_in[0];
    const float* k  = (const float*)d_in[1];
    const float* v  = (const float*)d_in[2];
    const float* wt = (const float*)d_in[3];
    const float* wp = (const float*)d_in[4];
    const float* wg = (const float*)d_in[5];
    const float* wo = (const float*)d_in[6];
    float* out = (float*)d_out;

    const size_t PROJ = (size_t)B_ * N_ * D_;   // 4,194,304 elems
    uint16_t* qp   = (uint16_t*)d_ws;
    uint16_t* kp   = qp + PROJ;
    uint16_t* vpT  = kp + PROJ;
    uint16_t* obuf = vpT + PROJ;
    uint16_t* bwt  = obuf + PROJ;
    uint16_t* bwp  = bwt + (size_t)D_ * C_;
    uint16_t* bwg  = bwp + (size_t)D_ * C_;
    uint16_t* bwo  = bwg + (size_t)D_ * C_;
    float* invd    = (float*)(bwo + (size_t)D_ * C_);
    // total ws use: 4*8MB + 4*64KB + 128KB ≈ 34 MB

    prep_weights<<<dim3(128), 256, 0, stream>>>(wt, wp, wg, wo, bwt, bwp, bwg, bwo);
    proj_kernel<<<dim3(N_ / 64, B_, 3), 256, 0, stream>>>(q, k, v, bwt, bwp, bwg, qp, kp, vpT);
    pass1_denom<<<dim3(N_ / 64, B_), 256, 0, stream>>>(qp, kp, invd);
    pass2_attn<<<dim3(N_ / 64, B_), 256, 0, stream>>>(qp, kp, vpT, invd, obuf);
    pass3_out<<<dim3(N_ / 64, B_), 256, 0, stream>>>(obuf, bwo, v, out);
}

// Round 5
// 431.873 us; speedup vs baseline: 1.6915x; 1.6915x over previous
//
#include <hip/hip_runtime.h>
#include <stdint.h>

#define B_ 8
#define C_ 256
#define D_ 128
#define N_ 4096

typedef __bf16 bf16x8 __attribute__((ext_vector_type(8)));
typedef uint16_t u16x8 __attribute__((ext_vector_type(8)));
typedef uint16_t u16x4 __attribute__((ext_vector_type(4)));
typedef float f32x4 __attribute__((ext_vector_type(4)));

__device__ inline uint16_t f2bf(float x) {
    union { float f; uint32_t u; } v; v.f = x;
    uint32_t u = v.u;
    return (uint16_t)((u + 0x7FFFu + ((u >> 16) & 1u)) >> 16);
}

// ---------------- prep: fp32 weights -> bf16 (scale 1/sqrt(D) folded into W_theta)
__global__ __launch_bounds__(256) void prep_weights(
    const float* __restrict__ wt, const float* __restrict__ wp,
    const float* __restrict__ wg, const float* __restrict__ wo,
    uint16_t* __restrict__ bwt, uint16_t* __restrict__ bwp,
    uint16_t* __restrict__ bwg, uint16_t* __restrict__ bwo)
{
    int i = blockIdx.x * 256 + threadIdx.x;   // 0..32767
    const float scale = 0.08838834764831845f; // 1/sqrt(128)
    bwt[i] = f2bf(wt[i] * scale);
    bwp[i] = f2bf(wp[i]);
    bwg[i] = f2bf(wg[i]);
    bwo[i] = f2bf(wo[i]);
}

// ---------------- projections: z=0 qp[B][N][D], z=1 kp[B][N][D], z=2 vpT[B][D][N]
__global__ __launch_bounds__(256) void proj_kernel(
    const float* __restrict__ q, const float* __restrict__ k, const float* __restrict__ v,
    const uint16_t* __restrict__ bwt, const uint16_t* __restrict__ bwp, const uint16_t* __restrict__ bwg,
    uint16_t* __restrict__ qp, uint16_t* __restrict__ kp, uint16_t* __restrict__ vpT)
{
    const int which = blockIdx.z;
    const float* src = (which == 0) ? q : ((which == 1) ? k : v);
    const uint16_t* w = (which == 0) ? bwt : ((which == 1) ? bwp : bwg);
    const int b   = blockIdx.y;
    const int n0  = blockIdx.x * 64;
    const int wav = threadIdx.x >> 6;
    const int lane = threadIdx.x & 63;
    const int col = lane & 15;
    const int quad = lane >> 4;
    const int n = n0 + wav * 16 + col;

    const float* srcb = src + (size_t)b * C_ * N_;

    f32x4 acc[8];
#pragma unroll
    for (int mf = 0; mf < 8; ++mf) acc[mf] = (f32x4){0.f, 0.f, 0.f, 0.f};

    for (int kc = 0; kc < 8; ++kc) {
        const int cbase = kc * 32 + quad * 8;
        u16x8 bb;
#pragma unroll
        for (int j = 0; j < 8; ++j)
            bb[j] = f2bf(srcb[(size_t)(cbase + j) * N_ + n]);
        bf16x8 bfrag = __builtin_bit_cast(bf16x8, bb);
#pragma unroll
        for (int mf = 0; mf < 8; ++mf) {
            bf16x8 afrag = *(const bf16x8*)(w + (size_t)(mf * 16 + col) * C_ + cbase);
            acc[mf] = __builtin_amdgcn_mfma_f32_16x16x32_bf16(afrag, bfrag, acc[mf], 0, 0, 0);
        }
    }

    if (which < 2) {
        uint16_t* dst = (which == 0) ? qp : kp;          // [B][N][D], d contiguous
        uint16_t* base = dst + ((size_t)b * N_ + n) * D_;
#pragma unroll
        for (int mf = 0; mf < 8; ++mf) {
            u16x4 pk;
#pragma unroll
            for (int r = 0; r < 4; ++r) pk[r] = f2bf(acc[mf][r]);
            *(u16x4*)(base + mf * 16 + quad * 4) = pk;
        }
    } else {
        uint16_t* base = vpT + (size_t)b * D_ * N_;       // [B][D][N], n contiguous
#pragma unroll
        for (int mf = 0; mf < 8; ++mf)
#pragma unroll
            for (int r = 0; r < 4; ++r) {
                int d = mf * 16 + quad * 4 + r;
                base[(size_t)d * N_ + n] = f2bf(acc[mf][r]);
            }
    }
}

// ---------------- pass 1: inv_denom[b][m] = 1 / sum_n exp(S[n][m])
__global__ __launch_bounds__(256) void pass1_denom(
    const uint16_t* __restrict__ qp, const uint16_t* __restrict__ kp,
    float* __restrict__ inv_denom)
{
    const int b  = blockIdx.y;
    const int m0 = blockIdx.x * 64;
    const int wav = threadIdx.x >> 6;
    const int lane = threadIdx.x & 63;
    const int col = lane & 15;
    const int quad = lane >> 4;

    const uint16_t* qpb = qp + (size_t)b * N_ * D_;
    const uint16_t* kpb = kp + (size_t)b * N_ * D_;

    bf16x8 bfr[4][4];
#pragma unroll
    for (int mf = 0; mf < 4; ++mf)
#pragma unroll
        for (int kc = 0; kc < 4; ++kc)
            bfr[mf][kc] = *(const bf16x8*)(kpb + (size_t)(m0 + mf * 16 + col) * D_ + kc * 32 + quad * 8);

    float colsum[4] = {0.f, 0.f, 0.f, 0.f};

    for (int it = 0; it < 64; ++it) {
        const int nbase = it * 64 + wav * 16;
        bf16x8 afr[4];
#pragma unroll
        for (int kc = 0; kc < 4; ++kc)
            afr[kc] = *(const bf16x8*)(qpb + (size_t)(nbase + col) * D_ + kc * 32 + quad * 8);
#pragma unroll
        for (int mf = 0; mf < 4; ++mf) {
            f32x4 acc = (f32x4){0.f, 0.f, 0.f, 0.f};
#pragma unroll
            for (int kc = 0; kc < 4; ++kc)
                acc = __builtin_amdgcn_mfma_f32_16x16x32_bf16(afr[kc], bfr[mf][kc], acc, 0, 0, 0);
#pragma unroll
            for (int r = 0; r < 4; ++r)
                colsum[mf] += __expf(acc[r]);
        }
    }

    __shared__ float cs[4][64];
#pragma unroll
    for (int mf = 0; mf < 4; ++mf) {
        float s = colsum[mf];
        s += __shfl_down(s, 16, 64);
        s += __shfl_down(s, 32, 64);
        if (quad == 0) cs[wav][mf * 16 + col] = s;
    }
    __syncthreads();
    if (threadIdx.x < 64) {
        float s = cs[0][threadIdx.x] + cs[1][threadIdx.x] + cs[2][threadIdx.x] + cs[3][threadIdx.x];
        inv_denom[(size_t)b * N_ + m0 + threadIdx.x] = 1.0f / s;
    }
}

// ---------------- pass 2 (v5, m97-style): O[n][d] = sum_m exp(S[n][m])*invd[m]*vp[m][d]
// LDS staging via global_load_lds DMA in FRAGMENT-MAJOR order: the per-lane global
// address is free; the LDS side is wave-uniform-base + lane*16. So each 1KB staging
// instruction writes one MFMA-ready fragment block, and every fragment read is a
// conflict-free stride-16 ds_read_b128. Double-buffered, one barrier per 32-m chunk.
// Rounds 2-4 proved the register-fragment path is TCP-BW bound (4x wave duplication,
// 288 KB/CU/iter): LDS sharing removes the duplication, DMA bypasses VGPR/TCP.
// XCD swizzle: batch = blockIdx.x & 7 -> all of a batch's 2 MB (kp+vpT) in one XCD L2.
__global__ __launch_bounds__(256) void pass2_attn(
    const uint16_t* __restrict__ qp, const uint16_t* __restrict__ kp,
    const uint16_t* __restrict__ vpT, const float* __restrict__ inv_denom,
    uint16_t* __restrict__ obuf)
{
    const int b  = blockIdx.x & 7;            // XCD-local batch (XCD = blockid % 8)
    const int n0 = (blockIdx.x >> 3) * 64;
    const int wav = threadIdx.x >> 6;
    const int lane = threadIdx.x & 63;
    const int col = lane & 15;
    const int quad = lane >> 4;

    const uint16_t* qpb = qp + (size_t)b * N_ * D_;
    const uint16_t* kpb = kp + (size_t)b * N_ * D_;
    const uint16_t* vtb = vpT + (size_t)b * D_ * N_;
    const float* invd = inv_denom + (size_t)b * N_;

    // 2 x 16 frag-blocks x 1KB staging + per-wave P-transpose tile
    __shared__ __align__(16) uint16_t stage[2][16 * 512];      // 32 KB
    __shared__ __align__(16) uint16_t plds_all[4][16][40];     // 5 KB
    uint16_t (*plds)[40] = plds_all[wav];

    // per-lane global source bases (element offsets)
    // kp frag (mf,kc): kpb + (m0+mf*16+col)*D + kc*32 + quad*8   -> fid = mf*4+kc (0..7)
    // vp frag (df):    vtb + (df*16+col)*N + m0 + quad*8         -> fid = 8+df    (8..15)
    const uint16_t* kp_lane = kpb + (size_t)col * D_ + quad * 8;
    const uint16_t* vt_lane = vtb + (size_t)col * N_ + quad * 8;

    // wave w stages fids w*4 .. w*4+3 (waves 0-1: kp, waves 2-3: vp)
#define STAGE(bufidx, m0_)                                                          \
    {                                                                               \
        uint16_t* lb = &stage[bufidx][0];                                           \
        _Pragma("unroll")                                                           \
        for (int j = 0; j < 4; ++j) {                                               \
            const int fid = wav * 4 + j;                                            \
            const uint16_t* g;                                                      \
            if (fid < 8)                                                            \
                g = kp_lane + (size_t)((m0_) + (fid >> 2) * 16) * D_ + (fid & 3) * 32; \
            else                                                                    \
                g = vt_lane + (size_t)((fid - 8) * 16) * N_ + (m0_);                \
            __builtin_amdgcn_global_load_lds(                                       \
                (const __attribute__((address_space(1))) unsigned int*)g,           \
                (__attribute__((address_space(3))) unsigned int*)(lb + fid * 512),  \
                16, 0, 0);                                                          \
        }                                                                           \
    }

    const int nrow = n0 + wav * 16 + col;
    bf16x8 qfr[4];
#pragma unroll
    for (int kc = 0; kc < 4; ++kc)
        qfr[kc] = *(const bf16x8*)(qpb + (size_t)nrow * D_ + kc * 32 + quad * 8);

    f32x4 oacc[8];
#pragma unroll
    for (int df = 0; df < 8; ++df) oacc[df] = (f32x4){0.f, 0.f, 0.f, 0.f};

    STAGE(0, 0);
    __syncthreads();   // drain prologue DMA (vmcnt 0) + barrier

    for (int chunk = 0; chunk < N_ / 32; ++chunk) {
        const int m0 = chunk * 32;
        const int cur = chunk & 1;
        STAGE(cur ^ 1, (m0 + 32) & (N_ - 1));   // prefetch next chunk (last iter: dead)

        const uint16_t* sb = &stage[cur][0];
        // S = QP.KP^T (16n x 32m), frag reads are stride-16 conflict-free b128
        f32x4 sacc0 = (f32x4){0.f, 0.f, 0.f, 0.f};
        f32x4 sacc1 = (f32x4){0.f, 0.f, 0.f, 0.f};
#pragma unroll
        for (int kc = 0; kc < 4; ++kc) {
            bf16x8 b0 = *(const bf16x8*)(sb + (size_t)kc * 512 + lane * 8);
            sacc0 = __builtin_amdgcn_mfma_f32_16x16x32_bf16(qfr[kc], b0, sacc0, 0, 0, 0);
        }
#pragma unroll
        for (int kc = 0; kc < 4; ++kc) {
            bf16x8 b1 = *(const bf16x8*)(sb + (size_t)(4 + kc) * 512 + lane * 8);
            sacc1 = __builtin_amdgcn_mfma_f32_16x16x32_bf16(qfr[kc], b1, sacc1, 0, 0, 0);
        }
        const float inv0 = invd[m0 + col];
        const float inv1 = invd[m0 + 16 + col];
#pragma unroll
        for (int r = 0; r < 4; ++r) {
            plds[quad * 4 + r][col]      = f2bf(__expf(sacc0[r]) * inv0);
            plds[quad * 4 + r][16 + col] = f2bf(__expf(sacc1[r]) * inv1);
        }
        // per-wave region: same-wave ds ordering via lgkmcnt, no barrier needed here
        bf16x8 pfrag = *(const bf16x8*)&plds[col][quad * 8];   // A-layout: n=col, k=m
#pragma unroll
        for (int df = 0; df < 8; ++df) {
            bf16x8 vfr = *(const bf16x8*)(sb + (size_t)(8 + df) * 512 + lane * 8);
            oacc[df] = __builtin_amdgcn_mfma_f32_16x16x32_bf16(pfrag, vfr, oacc[df], 0, 0, 0);
        }
        __syncthreads();   // all waves done reading cur + own prefetch DMA drained
    }
#undef STAGE

    uint16_t* ob = obuf + ((size_t)b * N_ + n0 + wav * 16) * D_;   // [B][N][D]
#pragma unroll
    for (int df = 0; df < 8; ++df)
#pragma unroll
        for (int r = 0; r < 4; ++r)
            ob[(size_t)(quad * 4 + r) * D_ + df * 16 + col] = f2bf(oacc[df][r]);
}

// ---------------- pass 3: out[b][c][n] = v[b][c][n] + sum_d W_out[c][d] * O[n][d]
__global__ __launch_bounds__(256) void pass3_out(
    const uint16_t* __restrict__ obuf, const uint16_t* __restrict__ bwo,
    const float* __restrict__ v, float* __restrict__ out)
{
    const int b  = blockIdx.y;
    const int n0 = blockIdx.x * 64;
    const int wav = threadIdx.x >> 6;
    const int lane = threadIdx.x & 63;
    const int col = lane & 15;
    const int quad = lane >> 4;
    const int n = n0 + wav * 16 + col;

    const uint16_t* ob = obuf + (size_t)b * N_ * D_;
    const float* vb = v + (size_t)b * C_ * N_;
    float* outb = out + (size_t)b * C_ * N_;

    bf16x8 bfr[4];
#pragma unroll
    for (int kc = 0; kc < 4; ++kc)
        bfr[kc] = *(const bf16x8*)(ob + (size_t)n * D_ + kc * 32 + quad * 8);

#pragma unroll
    for (int cf = 0; cf < 16; ++cf) {
        f32x4 acc = (f32x4){0.f, 0.f, 0.f, 0.f};
#pragma unroll
        for (int kc = 0; kc < 4; ++kc) {
            bf16x8 afr = *(const bf16x8*)(bwo + (size_t)(cf * 16 + col) * D_ + kc * 32 + quad * 8);
            acc = __builtin_amdgcn_mfma_f32_16x16x32_bf16(afr, bfr[kc], acc, 0, 0, 0);
        }
#pragma unroll
        for (int r = 0; r < 4; ++r) {
            const int c = cf * 16 + quad * 4 + r;
            const size_t idx = (size_t)c * N_ + n;
            outb[idx] = vb[idx] + acc[r];
        }
    }
}

extern "C" void kernel_launch(void* const* d_in, const int* in_sizes, int n_in,
                              void* d_out, int out_size, void* d_ws, size_t ws_size,
                              hipStream_t stream) {
    const float* q  = (const float*)d_in[0];
    const float* k  = (const float*)d_in[1];
    const float* v  = (const float*)d_in[2];
    const float* wt = (const float*)d_in[3];
    const float* wp = (const float*)d_in[4];
    const float* wg = (const float*)d_in[5];
    const float* wo = (const float*)d_in[6];
    float* out = (float*)d_out;

    const size_t PROJ = (size_t)B_ * N_ * D_;   // 4,194,304 elems
    uint16_t* qp   = (uint16_t*)d_ws;
    uint16_t* kp   = qp + PROJ;
    uint16_t* vpT  = kp + PROJ;
    uint16_t* obuf = vpT + PROJ;
    uint16_t* bwt  = obuf + PROJ;
    uint16_t* bwp  = bwt + (size_t)D_ * C_;
    uint16_t* bwg  = bwp + (size_t)D_ * C_;
    uint16_t* bwo  = bwg + (size_t)D_ * C_;
    float* invd    = (float*)(bwo + (size_t)D_ * C_);
    // total ws use: 4*8MB + 4*64KB + 128KB ≈ 34 MB

    prep_weights<<<dim3(128), 256, 0, stream>>>(wt, wp, wg, wo, bwt, bwp, bwg, bwo);
    proj_kernel<<<dim3(N_ / 64, B_, 3), 256, 0, stream>>>(q, k, v, bwt, bwp, bwg, qp, kp, vpT);
    pass1_denom<<<dim3(N_ / 64, B_), 256, 0, stream>>>(qp, kp, invd);
    pass2_attn<<<dim3(512), 256, 0, stream>>>(qp, kp, vpT, invd, obuf);
    pass3_out<<<dim3(N_ / 64, B_), 256, 0, stream>>>(obuf, bwo, v, out);
}

// Round 7
// 427.322 us; speedup vs baseline: 1.7095x; 1.0106x over previous
//
#include <hip/hip_runtime.h>
#include <stdint.h>

#define B_ 8
#define C_ 256
#define D_ 128
#define N_ 4096

typedef __bf16 bf16x8 __attribute__((ext_vector_type(8)));
typedef uint16_t u16x8 __attribute__((ext_vector_type(8)));
typedef uint16_t u16x4 __attribute__((ext_vector_type(4)));
typedef float f32x4 __attribute__((ext_vector_type(4)));

__device__ inline uint16_t f2bf(float x) {
    union { float f; uint32_t u; } v; v.f = x;
    uint32_t u = v.u;
    return (uint16_t)((u + 0x7FFFu + ((u >> 16) & 1u)) >> 16);
}

// device exp2 via v_exp_f32 (D = 2^S0); __exp2f collides with glibc math.h here
__device__ inline float dexp2(float x) { return __builtin_amdgcn_exp2f(x); }

// ---------------- prep: fp32 weights -> bf16.
// W_theta absorbs 1/sqrt(D) * log2(e): S' = S*log2(e), so exp(S) == exp2(S').
__global__ __launch_bounds__(256) void prep_weights(
    const float* __restrict__ wt, const float* __restrict__ wp,
    const float* __restrict__ wg, const float* __restrict__ wo,
    uint16_t* __restrict__ bwt, uint16_t* __restrict__ bwp,
    uint16_t* __restrict__ bwg, uint16_t* __restrict__ bwo)
{
    int i = blockIdx.x * 256 + threadIdx.x;   // 0..32767
    const float scale = 0.127517431f;         // log2(e)/sqrt(128)
    bwt[i] = f2bf(wt[i] * scale);
    bwp[i] = f2bf(wp[i]);
    bwg[i] = f2bf(wg[i]);
    bwo[i] = f2bf(wo[i]);
}

// ---------------- projections: z=0 qp[B][N][D], z=1 kp[B][N][D], z=2 vpT[B][D][N]
__global__ __launch_bounds__(256) void proj_kernel(
    const float* __restrict__ q, const float* __restrict__ k, const float* __restrict__ v,
    const uint16_t* __restrict__ bwt, const uint16_t* __restrict__ bwp, const uint16_t* __restrict__ bwg,
    uint16_t* __restrict__ qp, uint16_t* __restrict__ kp, uint16_t* __restrict__ vpT)
{
    const int which = blockIdx.z;
    const float* src = (which == 0) ? q : ((which == 1) ? k : v);
    const uint16_t* w = (which == 0) ? bwt : ((which == 1) ? bwp : bwg);
    const int b   = blockIdx.y;
    const int n0  = blockIdx.x * 64;
    const int wav = threadIdx.x >> 6;
    const int lane = threadIdx.x & 63;
    const int col = lane & 15;
    const int quad = lane >> 4;
    const int n = n0 + wav * 16 + col;

    const float* srcb = src + (size_t)b * C_ * N_;

    f32x4 acc[8];
#pragma unroll
    for (int mf = 0; mf < 8; ++mf) acc[mf] = (f32x4){0.f, 0.f, 0.f, 0.f};

    for (int kc = 0; kc < 8; ++kc) {
        const int cbase = kc * 32 + quad * 8;
        u16x8 bb;
#pragma unroll
        for (int j = 0; j < 8; ++j)
            bb[j] = f2bf(srcb[(size_t)(cbase + j) * N_ + n]);
        bf16x8 bfrag = __builtin_bit_cast(bf16x8, bb);
#pragma unroll
        for (int mf = 0; mf < 8; ++mf) {
            bf16x8 afrag = *(const bf16x8*)(w + (size_t)(mf * 16 + col) * C_ + cbase);
            acc[mf] = __builtin_amdgcn_mfma_f32_16x16x32_bf16(afrag, bfrag, acc[mf], 0, 0, 0);
        }
    }

    if (which < 2) {
        uint16_t* dst = (which == 0) ? qp : kp;          // [B][N][D], d contiguous
        uint16_t* base = dst + ((size_t)b * N_ + n) * D_;
#pragma unroll
        for (int mf = 0; mf < 8; ++mf) {
            u16x4 pk;
#pragma unroll
            for (int r = 0; r < 4; ++r) pk[r] = f2bf(acc[mf][r]);
            *(u16x4*)(base + mf * 16 + quad * 4) = pk;
        }
    } else {
        uint16_t* base = vpT + (size_t)b * D_ * N_;       // [B][D][N], n contiguous
#pragma unroll
        for (int mf = 0; mf < 8; ++mf)
#pragma unroll
            for (int r = 0; r < 4; ++r) {
                int d = mf * 16 + quad * 4 + r;
                base[(size_t)d * N_ + n] = f2bf(acc[mf][r]);
            }
    }
}

// ---------------- pass 1: inv_denom[b][m] = 1 / sum_n exp2(S'[n][m])
// XCD swizzle: b = blockIdx.x & 7 -> each XCD's L2 holds only its batch's qp+kp (2 MB).
__global__ __launch_bounds__(256) void pass1_denom(
    const uint16_t* __restrict__ qp, const uint16_t* __restrict__ kp,
    float* __restrict__ inv_denom)
{
    const int b  = blockIdx.x & 7;
    const int m0 = (blockIdx.x >> 3) * 64;
    const int wav = threadIdx.x >> 6;
    const int lane = threadIdx.x & 63;
    const int col = lane & 15;
    const int quad = lane >> 4;

    const uint16_t* qpb = qp + (size_t)b * N_ * D_;
    const uint16_t* kpb = kp + (size_t)b * N_ * D_;

    bf16x8 bfr[4][4];
#pragma unroll
    for (int mf = 0; mf < 4; ++mf)
#pragma unroll
        for (int kc = 0; kc < 4; ++kc)
            bfr[mf][kc] = *(const bf16x8*)(kpb + (size_t)(m0 + mf * 16 + col) * D_ + kc * 32 + quad * 8);

    float colsum[4] = {0.f, 0.f, 0.f, 0.f};

    for (int it = 0; it < 64; ++it) {
        const int nbase = it * 64 + wav * 16;
        bf16x8 afr[4];
#pragma unroll
        for (int kc = 0; kc < 4; ++kc)
            afr[kc] = *(const bf16x8*)(qpb + (size_t)(nbase + col) * D_ + kc * 32 + quad * 8);
#pragma unroll
        for (int mf = 0; mf < 4; ++mf) {
            f32x4 acc = (f32x4){0.f, 0.f, 0.f, 0.f};
#pragma unroll
            for (int kc = 0; kc < 4; ++kc)
                acc = __builtin_amdgcn_mfma_f32_16x16x32_bf16(afr[kc], bfr[mf][kc], acc, 0, 0, 0);
#pragma unroll
            for (int r = 0; r < 4; ++r)
                colsum[mf] += dexp2(acc[r]);
        }
    }

    __shared__ float cs[4][64];
#pragma unroll
    for (int mf = 0; mf < 4; ++mf) {
        float s = colsum[mf];
        s += __shfl_down(s, 16, 64);
        s += __shfl_down(s, 32, 64);
        if (quad == 0) cs[wav][mf * 16 + col] = s;
    }
    __syncthreads();
    if (threadIdx.x < 64) {
        float s = cs[0][threadIdx.x] + cs[1][threadIdx.x] + cs[2][threadIdx.x] + cs[3][threadIdx.x];
        inv_denom[(size_t)b * N_ + m0 + threadIdx.x] = 1.0f / s;
    }
}

// ---------------- pass 2 (v6, m-split x2): partial O over half the m range.
// Round-5 showed pass2 grid-limited at 2 blocks/CU (Occupancy 22%) with no pipe
// saturated. Split m into 2 halves -> 1024 blocks -> 4 blocks/CU (LDS-capped),
// 16 waves/CU. Partials land in obuf0/obuf1; pass3 accumulates both via MFMA.
__global__ __launch_bounds__(256) void pass2_attn(
    const uint16_t* __restrict__ qp, const uint16_t* __restrict__ kp,
    const uint16_t* __restrict__ vpT, const float* __restrict__ inv_denom,
    uint16_t* __restrict__ obuf0, uint16_t* __restrict__ obuf1)
{
    const int b    = blockIdx.x & 7;            // XCD-local batch
    const int half = (blockIdx.x >> 3) & 1;     // m-half
    const int n0   = (blockIdx.x >> 4) * 64;
    const int wav = threadIdx.x >> 6;
    const int lane = threadIdx.x & 63;
    const int col = lane & 15;
    const int quad = lane >> 4;

    const uint16_t* qpb = qp + (size_t)b * N_ * D_;
    const uint16_t* kpb = kp + (size_t)b * N_ * D_;
    const uint16_t* vtb = vpT + (size_t)b * D_ * N_;
    const float* invd = inv_denom + (size_t)b * N_;

    __shared__ __align__(16) uint16_t stage[2][16 * 512];      // 32 KB
    __shared__ __align__(16) uint16_t plds_all[4][16][40];     // 5 KB
    uint16_t (*plds)[40] = plds_all[wav];

    const uint16_t* kp_lane = kpb + (size_t)col * D_ + quad * 8;
    const uint16_t* vt_lane = vtb + (size_t)col * N_ + quad * 8;

#define STAGE(bufidx, m0_)                                                          \
    {                                                                               \
        uint16_t* lb = &stage[bufidx][0];                                           \
        _Pragma("unroll")                                                           \
        for (int j = 0; j < 4; ++j) {                                               \
            const int fid = wav * 4 + j;                                            \
            const uint16_t* g;                                                      \
            if (fid < 8)                                                            \
                g = kp_lane + (size_t)((m0_) + (fid >> 2) * 16) * D_ + (fid & 3) * 32; \
            else                                                                    \
                g = vt_lane + (size_t)((fid - 8) * 16) * N_ + (m0_);                \
            __builtin_amdgcn_global_load_lds(                                       \
                (const __attribute__((address_space(1))) unsigned int*)g,           \
                (__attribute__((address_space(3))) unsigned int*)(lb + fid * 512),  \
                16, 0, 0);                                                          \
        }                                                                           \
    }

    const int nrow = n0 + wav * 16 + col;
    bf16x8 qfr[4];
#pragma unroll
    for (int kc = 0; kc < 4; ++kc)
        qfr[kc] = *(const bf16x8*)(qpb + (size_t)nrow * D_ + kc * 32 + quad * 8);

    f32x4 oacc[8];
#pragma unroll
    for (int df = 0; df < 8; ++df) oacc[df] = (f32x4){0.f, 0.f, 0.f, 0.f};

    const int mstart = half * (N_ / 2);
    STAGE(0, mstart);
    __syncthreads();   // drain prologue DMA + barrier

    for (int chunk = 0; chunk < (N_ / 2) / 32; ++chunk) {
        const int m0 = mstart + chunk * 32;
        const int cur = chunk & 1;
        STAGE(cur ^ 1, (m0 + 32) & (N_ - 1));   // prefetch next chunk (last iter: dead)

        const uint16_t* sb = &stage[cur][0];
        f32x4 sacc0 = (f32x4){0.f, 0.f, 0.f, 0.f};
        f32x4 sacc1 = (f32x4){0.f, 0.f, 0.f, 0.f};
#pragma unroll
        for (int kc = 0; kc < 4; ++kc) {
            bf16x8 b0 = *(const bf16x8*)(sb + (size_t)kc * 512 + lane * 8);
            sacc0 = __builtin_amdgcn_mfma_f32_16x16x32_bf16(qfr[kc], b0, sacc0, 0, 0, 0);
        }
#pragma unroll
        for (int kc = 0; kc < 4; ++kc) {
            bf16x8 b1 = *(const bf16x8*)(sb + (size_t)(4 + kc) * 512 + lane * 8);
            sacc1 = __builtin_amdgcn_mfma_f32_16x16x32_bf16(qfr[kc], b1, sacc1, 0, 0, 0);
        }
        const float inv0 = invd[m0 + col];
        const float inv1 = invd[m0 + 16 + col];
#pragma unroll
        for (int r = 0; r < 4; ++r) {
            plds[quad * 4 + r][col]      = f2bf(dexp2(sacc0[r]) * inv0);
            plds[quad * 4 + r][16 + col] = f2bf(dexp2(sacc1[r]) * inv1);
        }
        bf16x8 pfrag = *(const bf16x8*)&plds[col][quad * 8];   // A-layout: n=col, k=m
#pragma unroll
        for (int df = 0; df < 8; ++df) {
            bf16x8 vfr = *(const bf16x8*)(sb + (size_t)(8 + df) * 512 + lane * 8);
            oacc[df] = __builtin_amdgcn_mfma_f32_16x16x32_bf16(pfrag, vfr, oacc[df], 0, 0, 0);
        }
        __syncthreads();   // all waves done reading cur + own prefetch DMA drained
    }
#undef STAGE

    uint16_t* obufH = half ? obuf1 : obuf0;
    uint16_t* ob = obufH + ((size_t)b * N_ + n0 + wav * 16) * D_;   // [B][N][D]
#pragma unroll
    for (int df = 0; df < 8; ++df)
#pragma unroll
        for (int r = 0; r < 4; ++r)
            ob[(size_t)(quad * 4 + r) * D_ + df * 16 + col] = f2bf(oacc[df][r]);
}

// ---------------- pass 3: out[b][c][n] = v[b][c][n] + sum_d W_out[c][d]*(O0+O1)[n][d]
__global__ __launch_bounds__(256) void pass3_out(
    const uint16_t* __restrict__ obuf0, const uint16_t* __restrict__ obuf1,
    const uint16_t* __restrict__ bwo,
    const float* __restrict__ v, float* __restrict__ out)
{
    const int b  = blockIdx.y;
    const int n0 = blockIdx.x * 64;
    const int wav = threadIdx.x >> 6;
    const int lane = threadIdx.x & 63;
    const int col = lane & 15;
    const int quad = lane >> 4;
    const int n = n0 + wav * 16 + col;

    const uint16_t* ob0 = obuf0 + (size_t)b * N_ * D_;
    const uint16_t* ob1 = obuf1 + (size_t)b * N_ * D_;
    const float* vb = v + (size_t)b * C_ * N_;
    float* outb = out + (size_t)b * C_ * N_;

    bf16x8 bfr0[4], bfr1[4];
#pragma unroll
    for (int kc = 0; kc < 4; ++kc) {
        bfr0[kc] = *(const bf16x8*)(ob0 + (size_t)n * D_ + kc * 32 + quad * 8);
        bfr1[kc] = *(const bf16x8*)(ob1 + (size_t)n * D_ + kc * 32 + quad * 8);
    }

#pragma unroll
    for (int cf = 0; cf < 16; ++cf) {
        f32x4 acc = (f32x4){0.f, 0.f, 0.f, 0.f};
#pragma unroll
        for (int kc = 0; kc < 4; ++kc) {
            bf16x8 afr = *(const bf16x8*)(bwo + (size_t)(cf * 16 + col) * D_ + kc * 32 + quad * 8);
            acc = __builtin_amdgcn_mfma_f32_16x16x32_bf16(afr, bfr0[kc], acc, 0, 0, 0);
            acc = __builtin_amdgcn_mfma_f32_16x16x32_bf16(afr, bfr1[kc], acc, 0, 0, 0);
        }
#pragma unroll
        for (int r = 0; r < 4; ++r) {
            const int c = cf * 16 + quad * 4 + r;
            const size_t idx = (size_t)c * N_ + n;
            outb[idx] = vb[idx] + acc[r];
        }
    }
}

extern "C" void kernel_launch(void* const* d_in, const int* in_sizes, int n_in,
                              void* d_out, int out_size, void* d_ws, size_t ws_size,
                              hipStream_t stream) {
    const float* q  = (const float*)d_in[0];
    const float* k  = (const float*)d_in[1];
    const float* v  = (const float*)d_in[2];
    const float* wt = (const float*)d_in[3];
    const float* wp = (const float*)d_in[4];
    const float* wg = (const float*)d_in[5];
    const float* wo = (const float*)d_in[6];
    float* out = (float*)d_out;

    const size_t PROJ = (size_t)B_ * N_ * D_;   // 4,194,304 elems
    uint16_t* qp    = (uint16_t*)d_ws;
    uint16_t* kp    = qp + PROJ;
    uint16_t* vpT   = kp + PROJ;
    uint16_t* obuf0 = vpT + PROJ;
    uint16_t* bwt   = obuf0 + PROJ;
    uint16_t* bwp   = bwt + (size_t)D_ * C_;
    uint16_t* bwg   = bwp + (size_t)D_ * C_;
    uint16_t* bwo   = bwg + (size_t)D_ * C_;
    float* invd     = (float*)(bwo + (size_t)D_ * C_);
    uint16_t* obuf1 = (uint16_t*)(invd + (size_t)B_ * N_);
    // total ws use: 5*8MB + 4*64KB + 128KB ≈ 42 MB

    prep_weights<<<dim3(128), 256, 0, stream>>>(wt, wp, wg, wo, bwt, bwp, bwg, bwo);
    proj_kernel<<<dim3(N_ / 64, B_, 3), 256, 0, stream>>>(q, k, v, bwt, bwp, bwg, qp, kp, vpT);
    pass1_denom<<<dim3(512), 256, 0, stream>>>(qp, kp, invd);
    pass2_attn<<<dim3(1024), 256, 0, stream>>>(qp, kp, vpT, invd, obuf0, obuf1);
    pass3_out<<<dim3(N_ / 64, B_), 256, 0, stream>>>(obuf0, obuf1, bwo, v, out);
}